// Round 4
// baseline (92.792 us; speedup 1.0000x reference)
//
#include <hip/hip_runtime.h>

#define B_ 256
#define H_ 512
#define KF 256
#define BH 131072    // B_*H_
#define BH4 32768    // BH/4
#define H4 128       // H_/4

#define BM 64
#define BN 64
#define BK 16

__device__ __forceinline__ float sigmoidf_(float x) { return 1.0f / (1.0f + __expf(-x)); }
__device__ __forceinline__ float tanh_fast(float x) { return 2.0f / (1.0f + __expf(-2.0f * x)) - 1.0f; }
__device__ __forceinline__ float4 sig4(float4 v) {
    return make_float4(sigmoidf_(v.x), sigmoidf_(v.y), sigmoidf_(v.z), sigmoidf_(v.w));
}

#define MAC_LOOP()                                                         \
    _Pragma("unroll")                                                      \
    for (int kk = 0; kk < BK; ++kk) {                                      \
        const float4 a = *(const float4*)&As[kk][ty << 2];                 \
        const float4 w = *(const float4*)&Ws[kk][tx << 2];                 \
        const float a4[4] = {a.x, a.y, a.z, a.w};                          \
        const float w4[4] = {w.x, w.y, w.z, w.w};                          \
        _Pragma("unroll")                                                  \
        for (int i = 0; i < 4; ++i)                                        \
            _Pragma("unroll")                                              \
            for (int j = 0; j < 4; ++j)                                    \
                acc[i][j] = fmaf(a4[i], w4[j], acc[i][j]);                 \
    }

// ---------------------------------------------------------------------------
// 64x64-tile split-K partial GEMM over a 256-wide K-chunk, reg double-stage.
// ---------------------------------------------------------------------------
template<bool MUL>
__device__ __forceinline__ void gemm64(
    float (*As)[BM + 4], float (*Ws)[BN + 4],
    const float* __restrict__ abase, const float* __restrict__ rbase,
    const float* __restrict__ W, int Ktot, int ks,
    int bm, int bn, int nIter, float* __restrict__ p)
{
    const int tid = threadIdx.x;
    const int ty = tid >> 4, tx = tid & 15;
    const int lrow = tid >> 2, lcol = (tid & 3) << 2;
    const float* aptr = abase + (bm + lrow) * 512 + lcol;
    const float* rptr = MUL ? rbase + (bm + lrow) * 512 + lcol : nullptr;
    const float* wptr = W + (size_t)(bn + lrow) * Ktot + ks + lcol;

    float acc[4][4] = {};
    float4 av = *(const float4*)aptr;
    if (MUL) { const float4 rv = *(const float4*)rptr;
               av.x *= rv.x; av.y *= rv.y; av.z *= rv.z; av.w *= rv.w; }
    float4 wv = *(const float4*)wptr;

    for (int it = 0; it < nIter; ++it) {
        __syncthreads();
        As[lcol + 0][lrow] = av.x; As[lcol + 1][lrow] = av.y;
        As[lcol + 2][lrow] = av.z; As[lcol + 3][lrow] = av.w;
        Ws[lcol + 0][lrow] = wv.x; Ws[lcol + 1][lrow] = wv.y;
        Ws[lcol + 2][lrow] = wv.z; Ws[lcol + 3][lrow] = wv.w;
        __syncthreads();
        if (it < nIter - 1) {
            av = *(const float4*)(aptr + (it + 1) * BK);
            if (MUL) { const float4 rv = *(const float4*)(rptr + (it + 1) * BK);
                       av.x *= rv.x; av.y *= rv.y; av.z *= rv.z; av.w *= rv.w; }
            wv = *(const float4*)(wptr + (it + 1) * BK);
        }
        MAC_LOOP();
    }
    #pragma unroll
    for (int i = 0; i < 4; ++i) {
        const int m = bm + (ty << 2) + i;
        #pragma unroll
        for (int j = 0; j < 4; ++j)
            p[m * 512 + bn + (tx << 2) + j] = acc[i][j];
    }
}

// Variant for the Wh GEMM upper-K half: A = sigmoid(br + sum r_parts) * hidden,
// r-gate reduced inline from the 4 split-K r partials (no reduce_rz launch).
__device__ __forceinline__ void gemm64_rmul(
    float (*As)[BM + 4], float (*Ws)[BN + 4],
    const float* __restrict__ hidden, const float* __restrict__ rparts,
    const float* __restrict__ br, const float* __restrict__ W,
    int ks, int bm, int bn, float* __restrict__ p)
{
    const int tid = threadIdx.x;
    const int ty = tid >> 4, tx = tid & 15;
    const int lrow = tid >> 2, lcol = (tid & 3) << 2;
    const int off = ks - 512;
    const float* aptr = hidden + (bm + lrow) * 512 + off + lcol;
    const float* rptr = rparts + (bm + lrow) * 512 + off + lcol;
    const float* bptr = br + off + lcol;
    const float* wptr = W + (size_t)(bn + lrow) * 1024 + ks + lcol;

    float acc[4][4] = {};
    float4 av, wv;
    {
        float4 rs = *(const float4*)bptr;
        #pragma unroll
        for (int s = 0; s < 4; ++s) { const float4 rp = *(const float4*)(rptr + (size_t)s * BH);
            rs.x += rp.x; rs.y += rp.y; rs.z += rp.z; rs.w += rp.w; }
        const float4 hv = *(const float4*)aptr;
        av = make_float4(sigmoidf_(rs.x) * hv.x, sigmoidf_(rs.y) * hv.y,
                         sigmoidf_(rs.z) * hv.z, sigmoidf_(rs.w) * hv.w);
        wv = *(const float4*)wptr;
    }
    for (int it = 0; it < 16; ++it) {
        __syncthreads();
        As[lcol + 0][lrow] = av.x; As[lcol + 1][lrow] = av.y;
        As[lcol + 2][lrow] = av.z; As[lcol + 3][lrow] = av.w;
        Ws[lcol + 0][lrow] = wv.x; Ws[lcol + 1][lrow] = wv.y;
        Ws[lcol + 2][lrow] = wv.z; Ws[lcol + 3][lrow] = wv.w;
        __syncthreads();
        if (it < 15) {
            float4 rs = *(const float4*)(bptr + (it + 1) * BK);
            #pragma unroll
            for (int s = 0; s < 4; ++s) { const float4 rp = *(const float4*)(rptr + (size_t)s * BH + (it + 1) * BK);
                rs.x += rp.x; rs.y += rp.y; rs.z += rp.z; rs.w += rp.w; }
            const float4 hv = *(const float4*)(aptr + (it + 1) * BK);
            av = make_float4(sigmoidf_(rs.x) * hv.x, sigmoidf_(rs.y) * hv.y,
                             sigmoidf_(rs.z) * hv.z, sigmoidf_(rs.w) * hv.w);
            wv = *(const float4*)(wptr + (it + 1) * BK);
        }
        MAC_LOOP();
    }
    #pragma unroll
    for (int i = 0; i < 4; ++i) {
        const int m = bm + (ty << 2) + i;
        #pragma unroll
        for (int j = 0; j < 4; ++j)
            p[m * 512 + bn + (tx << 2) + j] = acc[i][j];
    }
}

// All input-only GEMM parts in one launch. z 0..5: d splits (K=1536) ->
// dbase slices 0..5; z 6..13: r (6..9) / z (10..13) splits -> rzbase 0..7.
__global__ __launch_bounds__(256) void k_gemm_drz(
    const float* __restrict__ sample, const float* __restrict__ hidden,
    const float* __restrict__ d0,
    const float* __restrict__ Wd, const float* __restrict__ Wr,
    const float* __restrict__ Wz,
    float* __restrict__ dbase, float* __restrict__ rzbase)
{
    __shared__ float As[BK][BM + 4];
    __shared__ float Ws[BK][BN + 4];
    const int z = blockIdx.z;
    if (z < 6) {
        const int ks = z << 8, seg = ks >> 9;
        const float* ab = (seg == 0 ? sample : (seg == 1 ? hidden : d0)) + (ks & 511);
        gemm64<false>(As, Ws, ab, nullptr, Wd, 1536, ks,
                      blockIdx.y * BM, blockIdx.x * BN, 16, dbase + (size_t)z * BH);
    } else {
        const int id = z - 6, gz = id >> 2, s = id & 3, ks = s << 8;
        const float* ab = (ks < 512 ? sample + ks : hidden + (ks - 512));
        gemm64<false>(As, Ws, ab, nullptr, gz ? Wz : Wr, 1024, ks,
                      blockIdx.y * BM, blockIdx.x * BN, 16, rzbase + (size_t)id * BH);
    }
}

// mega: blocks 0..127 = h-GEMM (r-gate inline); blocks 128..639 = full
// 256-step filter with inline dv reduce. d-parts live in hc1 slices 0..5
// (column-exclusive read-before-overwrite); acc stashed in hc1 slice 255.
__global__ __launch_bounds__(256) void k_mega(
    const float* __restrict__ ht, const float* __restrict__ bd,
    const float* __restrict__ sample, const float* __restrict__ hidden,
    const float* __restrict__ rparts, const float* __restrict__ br,
    const float* __restrict__ Wh, float* __restrict__ hparts,
    float* hc1, float* __restrict__ dv_out)
{
    if (blockIdx.x < 128) {
        __shared__ float As[BK][BM + 4];
        __shared__ float Ws[BK][BN + 4];
        const int id = blockIdx.x;
        const int s = id >> 5, t2 = id & 31;
        const int bn = (t2 >> 2) << 6, bm = (t2 & 3) << 6, ks = s << 8;
        if (ks < 512)
            gemm64<false>(As, Ws, sample + ks, nullptr, Wh, 1024, ks, bm, bn, 16,
                          hparts + (size_t)s * BH);
        else
            gemm64_rmul(As, Ws, hidden, rparts, br, Wh, ks, bm, bn,
                        hparts + (size_t)s * BH);
        return;
    }
    __shared__ float s_inv[KF], s_tinv[KF];
    const int tid = threadIdx.x;
    const float fi = 1.0f / (float)(tid + 1);
    s_inv[tid] = fi; s_tinv[tid] = (float)tid * fi;
    __syncthreads();

    const int g = (blockIdx.x - 128) * 256 + tid;
    const int n = g & (H_ - 1);
    float sd = bd[n];
    #pragma unroll
    for (int s = 0; s < 6; ++s) sd += hc1[(size_t)s * BH + g];
    const float d = 0.5f * sigmoidf_(sd);
    dv_out[g] = d;

    float c = 1.0f, acc = 0.0f;
    #pragma unroll 16
    for (int t = 0; t < KF; ++t) {
        const int k = KF - 1 - t;
        const float v = ht[(size_t)k * BH + g];
        c *= fmaf(-d, s_inv[t], s_tinv[t]);          // (t - d)/(t + 1)
        acc = fmaf(v, c, acc);
        if (k >= 1) hc1[(size_t)(k - 1) * BH + g] = v;
    }
    hc1[(size_t)(KF - 1) * BH + g] = acc;            // stash; finalize overwrites
}

// finalize: z reduce inline, sec = tanh(bh+sum h)*(1-z), hn = sec - acc
__global__ __launch_bounds__(256) void k_finalize(
    const float4* __restrict__ zparts, const float4* __restrict__ bz,
    const float4* __restrict__ hparts, const float4* __restrict__ bh,
    float4* hc1_4, float4* __restrict__ hn_out)
{
    const int g = blockIdx.x * 256 + threadIdx.x;
    const int n = g & (H4 - 1);
    float4 zs = bz[n], hs = bh[n];
    #pragma unroll
    for (int s = 0; s < 4; ++s) { const float4 p = zparts[(size_t)s * BH4 + g];
        zs.x += p.x; zs.y += p.y; zs.z += p.z; zs.w += p.w; }
    #pragma unroll
    for (int s = 0; s < 4; ++s) { const float4 p = hparts[(size_t)s * BH4 + g];
        hs.x += p.x; hs.y += p.y; hs.z += p.z; hs.w += p.w; }
    const float4 z = sig4(zs);
    const float4 a = hc1_4[(size_t)255 * BH4 + g];
    float4 hn;
    hn.x = tanh_fast(hs.x) * (1.0f - z.x) - a.x;
    hn.y = tanh_fast(hs.y) * (1.0f - z.y) - a.y;
    hn.z = tanh_fast(hs.z) * (1.0f - z.z) - a.z;
    hn.w = tanh_fast(hs.w) * (1.0f - z.w) - a.w;
    hn_out[g] = hn;
    hc1_4[(size_t)255 * BH4 + g] = hn;
}

__global__ __launch_bounds__(256) void k_gemm_o(
    const float* __restrict__ hn, const float* __restrict__ Wo,
    float* __restrict__ parts, int chunk)
{
    __shared__ float As[BK][BM + 4];
    __shared__ float Ws[BK][BN + 4];
    const int s = blockIdx.z, ks = s * chunk;
    gemm64<false>(As, Ws, hn + ks, nullptr, Wo, 512, ks,
                  blockIdx.y * BM, blockIdx.x * BN, chunk / BK, parts + (size_t)s * BH);
}

// no __restrict__: fallback path calls with parts == out (same-thread RMW)
__global__ __launch_bounds__(256) void k_reduce_o(
    const float4* parts, const float4* __restrict__ bo, float4* out, int NS)
{
    const int g = blockIdx.x * 256 + threadIdx.x;
    float4 v = bo[g & (H4 - 1)];
    for (int s = 0; s < NS; ++s) { const float4 p = parts[(size_t)s * BH4 + g];
        v.x += p.x; v.y += p.y; v.z += p.z; v.w += p.w; }
    out[g] = v;
}

// ------------------------- fallback-only kernels ---------------------------
__global__ __launch_bounds__(256) void k_reduce_rz(
    const float4* __restrict__ parts, const float4* __restrict__ br,
    const float4* __restrict__ bz, float4* __restrict__ rb, float4* __restrict__ zb)
{
    const int g = blockIdx.x * 256 + threadIdx.x;
    const int n = g & (H4 - 1);
    float4 r = br[n], z = bz[n];
    #pragma unroll
    for (int s = 0; s < 4; ++s) { const float4 p = parts[(size_t)s * BH4 + g];
        r.x += p.x; r.y += p.y; r.z += p.z; r.w += p.w; }
    #pragma unroll
    for (int s = 4; s < 8; ++s) { const float4 p = parts[(size_t)s * BH4 + g];
        z.x += p.x; z.y += p.y; z.z += p.z; z.w += p.w; }
    rb[g] = sig4(r); zb[g] = sig4(z);
}

__global__ __launch_bounds__(256) void k_gemm_h(
    const float* __restrict__ sample, const float* __restrict__ hidden,
    const float* __restrict__ rb, const float* __restrict__ Wh,
    float* __restrict__ parts)
{
    __shared__ float As[BK][BM + 4];
    __shared__ float Ws[BK][BN + 4];
    const int s = blockIdx.z, ks = s << 8;
    if (ks < 512)
        gemm64<false>(As, Ws, sample + ks, nullptr, Wh, 1024, ks,
                      blockIdx.y * BM, blockIdx.x * BN, 16, parts + (size_t)s * BH);
    else
        gemm64<true>(As, Ws, hidden + (ks - 512), rb + (ks - 512), Wh, 1024, ks,
                     blockIdx.y * BM, blockIdx.x * BN, 16, parts + (size_t)s * BH);
}

__global__ __launch_bounds__(256) void k_filter_full(
    const float* __restrict__ ht, const float* dparts, const float* __restrict__ bd,
    const float* zbuf, const float* hparts, const float* __restrict__ bh,
    float* hc1, float* __restrict__ dv_out, float* __restrict__ hn_out)
{
    __shared__ float s_inv[KF], s_tinv[KF];
    const int tid = threadIdx.x;
    const float fi = 1.0f / (float)(tid + 1);
    s_inv[tid] = fi; s_tinv[tid] = (float)tid * fi;
    __syncthreads();

    const int g = blockIdx.x * 256 + tid;
    const int n = g & (H_ - 1);
    float sd = bd[n];
    #pragma unroll
    for (int s = 0; s < 6; ++s) sd += dparts[(size_t)s * BH + g];
    const float d = 0.5f * sigmoidf_(sd);
    dv_out[g] = d;
    float sh = bh[n];
    #pragma unroll
    for (int s = 0; s < 4; ++s) sh += hparts[(size_t)s * BH + g];
    const float z = zbuf[g];

    float c = 1.0f, acc = 0.0f;
    #pragma unroll 16
    for (int t = 0; t < KF; ++t) {
        const int k = KF - 1 - t;
        const float v = ht[(size_t)k * BH + g];
        c *= fmaf(-d, s_inv[t], s_tinv[t]);
        acc = fmaf(v, c, acc);
        if (k >= 1) hc1[(size_t)(k - 1) * BH + g] = v;
    }
    const float hn = tanh_fast(sh) * (1.0f - z) - acc;
    hc1[(size_t)(KF - 1) * BH + g] = hn;
    hn_out[g] = hn;
}

extern "C" void kernel_launch(void* const* d_in, const int* in_sizes, int n_in,
                              void* d_out, int out_size, void* d_ws, size_t ws_size,
                              hipStream_t stream)
{
    const float* sample = (const float*)d_in[0];
    const float* hidden = (const float*)d_in[1];
    const float* ht     = (const float*)d_in[2];
    const float* d0     = (const float*)d_in[3];
    const float* Wd = (const float*)d_in[4];
    const float* bd = (const float*)d_in[5];
    const float* Wr = (const float*)d_in[6];
    const float* br = (const float*)d_in[7];
    const float* Wz = (const float*)d_in[8];
    const float* bz = (const float*)d_in[9];
    const float* Wh = (const float*)d_in[10];
    const float* bh = (const float*)d_in[11];
    const float* Wo = (const float*)d_in[12];
    const float* bo = (const float*)d_in[13];

    float* out     = (float*)d_out;
    float* out_o   = out;
    float* out_hn  = out + BH;
    float* out_hc1 = out + 2 * BH;
    float* out_dv  = out + 2 * BH + (size_t)KF * BH;

    const size_t slice = BH;
    const size_t need = 12ull * slice * sizeof(float);

    if (ws_size >= need) {
        float* ws = (float*)d_ws;
        // ws slices: r parts 0..3, z parts 4..7, h parts 8..11; op reuses 0..3
        // d-parts -> hc1 slices 0..5 (dead until filter reads+overwrites them)
        k_gemm_drz<<<dim3(8, 4, 14), 256, 0, stream>>>(sample, hidden, d0,
                                                       Wd, Wr, Wz, out_hc1, ws);
        k_mega<<<dim3(640), 256, 0, stream>>>(ht, bd, sample, hidden,
                                              ws /*r parts*/, br, Wh,
                                              ws + 8 * slice /*h parts*/,
                                              out_hc1, out_dv);
        k_finalize<<<dim3(128), 256, 0, stream>>>(
            (const float4*)(ws + 4 * slice), (const float4*)bz,
            (const float4*)(ws + 8 * slice), (const float4*)bh,
            (float4*)out_hc1, (float4*)out_hn);
        k_gemm_o<<<dim3(8, 4, 4), 256, 0, stream>>>(out_hn, Wo, ws, 128);
        k_reduce_o<<<dim3(128), 256, 0, stream>>>((const float4*)ws,
                                                  (const float4*)bo,
                                                  (float4*)out_o, 4);
    } else {
        // serial fallback, scratch = dead hc1 slices
        float* sl = out_hc1;
        k_gemm_drz<<<dim3(8, 4, 14), 256, 0, stream>>>(sample, hidden, d0,
                                                       Wd, Wr, Wz, sl, sl + 6 * slice);
        k_reduce_rz<<<dim3(128), 256, 0, stream>>>((const float4*)(sl + 6 * slice),
                                                   (const float4*)br, (const float4*)bz,
                                                   (float4*)(sl + 14 * slice),
                                                   (float4*)(sl + 15 * slice));
        k_gemm_h<<<dim3(8, 4, 4), 256, 0, stream>>>(sample, hidden, sl + 14 * slice, Wh,
                                                    sl + 16 * slice);
        k_filter_full<<<dim3(512), 256, 0, stream>>>(ht, sl, bd, sl + 15 * slice,
                                                     sl + 16 * slice, bh,
                                                     out_hc1, out_dv, out_hn);
        k_gemm_o<<<dim3(8, 4, 1), 256, 0, stream>>>(out_hn, Wo, out_o, 512);
        k_reduce_o<<<dim3(128), 256, 0, stream>>>((const float4*)out_o, (const float4*)bo,
                                                  (float4*)out_o, 1);
    }
}